// Round 16
// baseline (613.675 us; speedup 1.0000x reference)
//
#include <hip/hip_runtime.h>
#include <cstdint>

typedef unsigned short u16;
typedef __bf16 bf16x8 __attribute__((ext_vector_type(8)));
typedef float f32x4 __attribute__((ext_vector_type(4)));

__device__ __forceinline__ float bf2f(u16 h) {
  union { uint32_t u; float f; } v; v.u = (uint32_t)h << 16; return v.f;
}
__device__ __forceinline__ u16 f2bf(float f) {
  union { float f; uint32_t u; } v; v.f = f;
  uint32_t r = v.u + 0x7fffu + ((v.u >> 16) & 1u);
  return (u16)(r >> 16);
}
__device__ __forceinline__ float sigmoidf_(float x) {
  return 1.0f / (1.0f + __expf(-x));
}
__device__ __forceinline__ void load_lds16(const void* g, void* l) {
  __builtin_amdgcn_global_load_lds(
      (const __attribute__((address_space(1))) void*)g,
      (__attribute__((address_space(3))) void*)l, 16, 0, 0);
}
__device__ __forceinline__ bf16x8 cvt8(const float* p) {
  float4 a = *(const float4*)p, b = *(const float4*)(p + 4);
  union { u16 u[8]; bf16x8 v; } r;
  r.u[0] = f2bf(a.x); r.u[1] = f2bf(a.y); r.u[2] = f2bf(a.z); r.u[3] = f2bf(a.w);
  r.u[4] = f2bf(b.x); r.u[5] = f2bf(b.y); r.u[6] = f2bf(b.z); r.u[7] = f2bf(b.w);
  return r.v;
}
#define BAR() __builtin_amdgcn_s_barrier()

// ------------- transpose+convert: in f32 [K][N] -> out bf16 [N][K] -------
__global__ __launch_bounds__(256) void transpose_cvt(
    const float* __restrict__ in, u16* __restrict__ out, int K, int N) {
  __shared__ float t[32][33];
  int n0 = blockIdx.x * 32, k0 = blockIdx.y * 32;
  int tx = threadIdx.x & 31, ty = threadIdx.x >> 5;
#pragma unroll
  for (int i = 0; i < 32; i += 8)
    t[ty + i][tx] = in[(long)(k0 + ty + i) * N + n0 + tx];
  __syncthreads();
#pragma unroll
  for (int i = 0; i < 32; i += 8)
    out[(long)(n0 + ty + i) * K + k0 + tx] = f2bf(t[tx][ty + i]);
}

// ===== MFMA projection: q = xq@wq+bq, k = xk@wk+bk ; [T,1024]->[T,16]x2 ===
template <int SAME, int QBF>
__global__ __launch_bounds__(256) void proj_mfma(
    const void* __restrict__ xq_, const float* __restrict__ xk,
    const float* __restrict__ wq, const float* __restrict__ bq,
    const float* __restrict__ wk, const float* __restrict__ bk,
    float* __restrict__ qout, float* __restrict__ kout) {
  __shared__ __attribute__((aligned(16))) u16 wt[2][16384];  // 64KB
  const int tid = threadIdx.x;
  for (int kq = 0; kq < 4; kq++) {
    int k = kq * 256 + tid;
    const float4* q4 = (const float4*)(wq + (long)k * 16);
    const float4* k4 = (const float4*)(wk + (long)k * 16);
#pragma unroll
    for (int p = 0; p < 4; p++) {
      float4 qv = q4[p], kv = k4[p];
      float qf[4] = {qv.x, qv.y, qv.z, qv.w};
      float kf[4] = {kv.x, kv.y, kv.z, kv.w};
#pragma unroll
      for (int j = 0; j < 4; j++) {
        int c = p * 4 + j;
        int off = (c * 2048 + k * 2) ^ ((c & 7) << 4);
        *(u16*)((char*)wt[0] + off) = f2bf(qf[j]);
        *(u16*)((char*)wt[1] + off) = f2bf(kf[j]);
      }
    }
  }
  __syncthreads();
  const int wv = tid >> 6, lane = tid & 63;
  const int lrow = lane & 15, g = lane >> 4;
  const long tok0 = (long)blockIdx.x * 64 + wv * 16;
  const int swz = (lrow & 7) << 4;
  const long arow = (tok0 + lrow) * 1024 + g * 8;
  f32x4 accq = {}, acck = {};
#pragma unroll 8
  for (int ks = 0; ks < 32; ks++) {
    bf16x8 aq_;
    if (QBF)
      aq_ = *(const bf16x8*)((const u16*)xq_ + arow + ks * 32);
    else
      aq_ = cvt8((const float*)xq_ + arow + ks * 32);
    bf16x8 ak_;
    if (SAME)
      ak_ = aq_;
    else
      ak_ = cvt8(xk + arow + ks * 32);
    int off = (lrow * 2048 + ks * 64 + g * 16) ^ swz;
    bf16x8 bq_ = *(const bf16x8*)((const char*)wt[0] + off);
    bf16x8 bk_ = *(const bf16x8*)((const char*)wt[1] + off);
    accq = __builtin_amdgcn_mfma_f32_16x16x32_bf16(aq_, bq_, accq, 0, 0, 0);
    acck = __builtin_amdgcn_mfma_f32_16x16x32_bf16(ak_, bk_, acck, 0, 0, 0);
  }
  const int col = lrow, r0 = g * 4;
  float bqv = bq[col], bkv = bk[col];
#pragma unroll
  for (int i = 0; i < 4; i++) {
    qout[(tok0 + r0 + i) * 16 + col] = accq[i] + bqv;
    kout[(tok0 + r0 + i) * 16 + col] = acck[i] + bkv;
  }
}

// ===== ksum: y_part[b][p][h][c] = Σ_{s in chunk} σ(k[b,s,h])·x[b,s,c] ====
__global__ __launch_bounds__(256) void ksum(const float* __restrict__ kp,
                                            const float* __restrict__ x,
                                            float* __restrict__ ypart,
                                            float* __restrict__ spart) {
  __shared__ __attribute__((aligned(16))) float sk[256][20];
  __shared__ float ssl[16][17];
  const int tid = threadIdx.x;
  const int cc = blockIdx.x, sc = blockIdx.y, b = blockIdx.z;
  const int cl = tid & 63, sg = tid >> 6;
  const int col0 = cc * 128 + cl;
  float acc0[16], acc1[16];
#pragma unroll
  for (int h = 0; h < 16; h++) { acc0[h] = 0.f; acc1[h] = 0.f; }
  float ss = 0.f;
  for (int tile = 0; tile < 2; tile++) {
    const int s0 = sc * 512 + tile * 256;
    const float* kr = kp + ((long)b * 4096 + s0 + tid) * 16;
#pragma unroll
    for (int p = 0; p < 4; p++) {
      float4 k4 = *(const float4*)(kr + p * 4);
      *(float4*)&sk[tid][p * 4] = make_float4(
          sigmoidf_(k4.x), sigmoidf_(k4.y), sigmoidf_(k4.z), sigmoidf_(k4.w));
    }
    __syncthreads();
    {
      int g2 = tid >> 4, h2 = tid & 15;
      float s_ = 0.f;
#pragma unroll
      for (int i = 0; i < 16; i++) s_ += sk[g2 * 16 + i][h2];
      ssl[g2][h2] = s_;
    }
    __syncthreads();
    if (tid < 16) {
      float s_ = 0.f;
#pragma unroll
      for (int gg = 0; gg < 16; gg++) s_ += ssl[gg][tid];
      ss += s_;
    }
    const float* xr = x + ((long)b * 4096 + s0 + sg * 64) * 1024 + col0;
    for (int j = 0; j < 64; j++) {
      float xv0 = xr[(long)j * 1024];
      float xv1 = xr[(long)j * 1024 + 64];
      const float4* skr = (const float4*)sk[sg * 64 + j];
#pragma unroll
      for (int p = 0; p < 4; p++) {
        float4 s4 = skr[p];
        acc0[p * 4 + 0] += s4.x * xv0; acc1[p * 4 + 0] += s4.x * xv1;
        acc0[p * 4 + 1] += s4.y * xv0; acc1[p * 4 + 1] += s4.y * xv1;
        acc0[p * 4 + 2] += s4.z * xv0; acc1[p * 4 + 2] += s4.z * xv1;
        acc0[p * 4 + 3] += s4.w * xv0; acc1[p * 4 + 3] += s4.w * xv1;
      }
    }
    __syncthreads();
  }
  long pbase = (long)(b * 32 + sc * 4 + sg) * 16384 + col0;
#pragma unroll
  for (int h = 0; h < 16; h++) {
    ypart[pbase + h * 1024] = acc0[h];
    ypart[pbase + h * 1024 + 64] = acc1[h];
  }
  if (tid < 16) spart[(b * 8 + sc) * 16 + tid] = ss;
}

// ===== kv[b,h,d] = (Σ_p y_part)·wv[:,h*64+d] + (Σσ)·bv[h*64+d] ===========
__global__ __launch_bounds__(256) void kv_small(
    const float* __restrict__ ypart, const float* __restrict__ spart,
    const float* __restrict__ wvw, const float* __restrict__ bv,
    float* __restrict__ kv) {
  __shared__ float yl[1024];
  __shared__ float red[4][64];
  const int tid = threadIdx.x;
  const int b = blockIdx.x >> 4, h = blockIdx.x & 15;
  for (int c = tid; c < 1024; c += 256) {
    float s_ = 0.f;
    const float* yp = ypart + (long)(b * 32) * 16384 + h * 1024 + c;
#pragma unroll
    for (int p = 0; p < 32; p++) s_ += yp[(long)p * 16384];
    yl[c] = s_;
  }
  __syncthreads();
  const int wv_ = tid >> 6, d = tid & 63;
  float acc = 0.f;
  const float* wcol = wvw + h * 64 + d;
  for (int c = wv_ * 256; c < wv_ * 256 + 256; c++)
    acc += yl[c] * wcol[(long)c * 1024];
  red[wv_][d] = acc;
  __syncthreads();
  if (tid < 64) {
    float ss = 0.f;
#pragma unroll
    for (int s_ = 0; s_ < 8; s_++) ss += spart[(b * 8 + s_) * 16 + h];
    kv[(b * 16 + h) * 64 + tid] = red[0][tid] + red[1][tid] + red[2][tid] +
                                  red[3][tid] + ss * bv[h * 64 + tid];
  }
}

// ===== z[b,h,n] = Σ_d cumsum_h(kv)[b,h,d]·wo[h*64+d, n]  (cumsum fused) ===
__global__ __launch_bounds__(256) void zker(const float* __restrict__ kvb,
                                            const float* __restrict__ wo,
                                            float* __restrict__ z) {
  __shared__ float sc_[64];
  const int tid = threadIdx.x;
  const int b = blockIdx.x >> 4, h = blockIdx.x & 15;
  if (tid < 64) {
    float run = 0.f;
    for (int hh = 0; hh <= h; hh++) run += kvb[(b * 16 + hh) * 64 + tid];
    sc_[tid] = run;
  }
  __syncthreads();
  float4 acc = make_float4(0.f, 0.f, 0.f, 0.f);
  for (int d = 0; d < 64; d++) {
    float s_ = sc_[d];
    float4 w = ((const float4*)(wo + (long)(h * 64 + d) * 1024))[tid];
    acc.x += s_ * w.x; acc.y += s_ * w.y;
    acc.z += s_ * w.z; acc.w += s_ * w.w;
  }
  ((float4*)(z + (long)(b * 16 + h) * 1024))[tid] = acc;
}

// ===== fused attn-broadcast + residual + LayerNorm ========================
template <int OMODE>  // 1: f32 out only; 2: f32 + bf16
__global__ __launch_bounds__(256) void ln_attn(
    const float* __restrict__ qp, const float* __restrict__ z,
    const float* __restrict__ bo, const float* __restrict__ r,
    const float* __restrict__ g, const float* __restrict__ be,
    float* __restrict__ outf, u16* __restrict__ outb) {
  __shared__ float zs[16][1024];
  __shared__ float sq16[16];
  __shared__ float s1[4], s2[4];
  const int tid = threadIdx.x;
  const int b = blockIdx.x >> 8;
  const float4* zg = (const float4*)(z + (long)b * 16384);
  float4* zl = (float4*)zs;
#pragma unroll
  for (int i = 0; i < 16; i++) zl[i * 256 + tid] = zg[i * 256 + tid];
  float4 gv = ((const float4*)g)[tid];
  float4 bev = ((const float4*)be)[tid];
  float4 bov = ((const float4*)bo)[tid];
  const int wid = tid >> 6, lane = tid & 63;
  for (int rr_ = 0; rr_ < 16; rr_++) {
    long row = (long)blockIdx.x * 16 + rr_;
    if (tid < 16) sq16[tid] = sigmoidf_(qp[row * 16 + tid]);
    __syncthreads();
    float4 rv = ((const float4*)(r + row * 1024))[tid];
    float y0 = bov.x + rv.x, y1 = bov.y + rv.y;
    float y2 = bov.z + rv.z, y3 = bov.w + rv.w;
#pragma unroll
    for (int h = 0; h < 16; h++) {
      float s_ = sq16[h];
      float4 zv = *(const float4*)&zs[h][tid * 4];
      y0 += s_ * zv.x; y1 += s_ * zv.y; y2 += s_ * zv.z; y3 += s_ * zv.w;
    }
    float s = y0 + y1 + y2 + y3;
    float q = y0 * y0 + y1 * y1 + y2 * y2 + y3 * y3;
#pragma unroll
    for (int o = 32; o > 0; o >>= 1) {
      s += __shfl_down(s, o);
      q += __shfl_down(q, o);
    }
    if (lane == 0) { s1[wid] = s; s2[wid] = q; }
    __syncthreads();
    s = s1[0] + s1[1] + s1[2] + s1[3];
    q = s2[0] + s2[1] + s2[2] + s2[3];
    float mu = s * (1.f / 1024.f);
    float var = q * (1.f / 1024.f) - mu * mu;
    float inv = rsqrtf(fmaxf(var, 0.f) + 1e-6f);
    float o0 = gv.x * (y0 - mu) * inv + bev.x;
    float o1 = gv.y * (y1 - mu) * inv + bev.y;
    float o2 = gv.z * (y2 - mu) * inv + bev.z;
    float o3 = gv.w * (y3 - mu) * inv + bev.w;
    ((float4*)(outf + row * 1024))[tid] = make_float4(o0, o1, o2, o3);
    if (OMODE == 2) {
      uint2 ob;
      ob.x = (uint32_t)f2bf(o0) | ((uint32_t)f2bf(o1) << 16);
      ob.y = (uint32_t)f2bf(o2) | ((uint32_t)f2bf(o3) << 16);
      ((uint2*)(outb + row * 1024))[tid] = ob;
    }
    __syncthreads();
  }
}

// ===== 256x128 MFMA GEMM — 2 blocks/CU TLP variant ========================
// C[M,N] = act(A[M,K]bf16 @ BT[N,K]^T + bias). M%256==0, N%128==0, K%64==0.
// 512 thr = 8 waves (4m x 2n), per-wave 64x64 (acc[4][4] = 64 AGPR).
// LDS 48KB = 2 slots x {A 256x32 (16KB) + B 128x32 (8KB)}, 2-bit slot
// permutation (src esrc / read slotr, involution). launch_bounds(512,4)
// -> 2 blocks/CU, 4 waves/SIMD: cross-block overlap hides stage+barrier.
// Phase per 32-wide ktile (ONE barrier): {8 ds_read; 3-load stage(next);
// lgkm0; 16 MFMA (setprio); vmcnt(0) AFTER MFMA (stage covered by MMA
// duration ~1200cyc > HBM 900); s_barrier}. Accum order bit-identical to
// the BK=64 version (same k sequence).
template <int ACT>
__global__ __launch_bounds__(512, 4) void gemm256(
    const u16* __restrict__ A, const u16* __restrict__ BT,
    const float* __restrict__ bias, u16* __restrict__ C, int M, int N,
    int K) {
  __shared__ __attribute__((aligned(16))) u16 lds[24576];  // 48 KB
  const int tid = threadIdx.x;
  const int wid = tid >> 6, lane = tid & 63;
  const int wm = wid >> 1, wn = wid & 1;  // 4m x 2n
  const int lrow = lane & 15, g = lane >> 4;

  int nwg = gridDim.x * gridDim.y;
  int orig = blockIdx.y * gridDim.x + blockIdx.x;
  int wg = (nwg & 7) ? orig : ((orig & 7) * (nwg >> 3) + (orig >> 3));
  const long bn = (long)(wg % gridDim.x) * 128;
  const long bm = (long)(wg / gridDim.x) * 256;

  const int rr = wid * 16 + (lane >> 2);                       // 0..127
  const int esrc = (((lane & 3) ^ ((lane >> 3) & 3)) * 8);     // src slot perm
  const u16* Abase = A + (bm + rr) * (long)K + esrc;
  const u16* Bbase = BT + (bn + rr) * (long)K + esrc;
  const long jstep = (long)128 * K;
  char* ldsc = (char*)lds;
  const int ldsw = wid * 1024;

  const int slotr = (g ^ ((lrow >> 1) & 3)) * 16;              // read slot perm
  const int aoff0 = (wm * 64 + lrow) * 64 + slotr;             // A region 16KB
  const int boff0 = 16384 + (wn * 64 + lrow) * 64 + slotr;     // B region 8KB

  f32x4 acc[4][4] = {};
  const int KT = K >> 5;  // 32-wide ktiles

  auto stage = [&](int s, int kt) {  // 3 x global_load_lds
    const u16* sA = Abase + (long)kt * 32;
    const u16* sB = Bbase + (long)kt * 32;
    int d = s * 24576 + ldsw;
    load_lds16(sA, ldsc + d);                  // A rows 0-127
    load_lds16(sA + jstep, ldsc + d + 8192);   // A rows 128-255
    load_lds16(sB, ldsc + d + 16384);          // B rows 0-127
  };

#define LDAB(S)                                                             \
  {                                                                         \
    const char* _b = ldsc + (S) * 24576;                                    \
    _Pragma("unroll") for (int m = 0; m < 4; m++)                           \
        af[m] = *(const bf16x8*)(_b + aoff0 + m * 1024);                    \
    _Pragma("unroll") for (int n = 0; n < 4; n++)                           \
        bq[n] = *(const bf16x8*)(_b + boff0 + n * 1024);                    \
  }
#define MMA16()                                                             \
  __builtin_amdgcn_s_setprio(1);                                            \
  _Pragma("unroll") for (int m = 0; m < 4; m++)                             \
  _Pragma("unroll") for (int n = 0; n < 4; n++)                             \
      acc[m][n] = __builtin_amdgcn_mfma_f32_16x16x32_bf16(af[m], bq[n],     \
                                                          acc[m][n], 0, 0,  \
                                                          0);               \
  __builtin_amdgcn_s_setprio(0);
#define WLG0() asm volatile("s_waitcnt lgkmcnt(0)" ::: "memory")
#define WVM0() asm volatile("s_waitcnt vmcnt(0)" ::: "memory")

  bf16x8 af[4], bq[4];

  stage(0, 0);
  WVM0();
  BAR();

  for (int kt = 0; kt + 1 < KT; ++kt) {
    const int s = kt & 1;
    LDAB(s);
    stage(s ^ 1, kt + 1);
    WLG0();
    MMA16();
    WVM0();  // stage landed under MFMA
    BAR();
  }
  {  // final ktile (no staging)
    LDAB((KT - 1) & 1);
    WLG0();
    MMA16();
    BAR();
  }

  // ---- epilogue: halves of 128 rows through LDS, coalesced uint4 stores --
  const uint4* lv = (const uint4*)lds;
#pragma unroll
  for (int half = 0; half < 2; half++) {
    BAR();
    if ((wm >> 1) == half) {
#pragma unroll
      for (int n = 0; n < 4; n++) {
        int cl = wn * 64 + n * 16 + lrow;
        float bb = bias[bn + cl];
#pragma unroll
        for (int m = 0; m < 4; m++) {
          int rl = (wm & 1) * 64 + m * 16 + g * 4;
#pragma unroll
          for (int i = 0; i < 4; i++) {
            float v = acc[m][n][i] + bb;
            if (ACT == 1) v = fmaxf(v, 0.f);
            lds[(rl + i) * 128 + cl] = f2bf(v);
          }
        }
      }
    }
    BAR();
#pragma unroll
    for (int it = 0; it < 4; it++) {
      int idx = it * 512 + tid;        // 2048 uint4 = 128x128 bf16
      int row = idx >> 4;              // 16 uint4 per 128-col row
      int cu = (idx & 15) * 8;
      *(uint4*)&C[(bm + half * 128 + row) * (long)N + bn + cu] = lv[idx];
    }
  }
#undef LDAB
#undef MMA16
#undef WLG0
#undef WVM0
}

// --- LayerNorm(a_bf16 + r_f32)*g + be -> f32 ------------------------------
__global__ __launch_bounds__(256) void ln_res(const u16* __restrict__ a,
                                              const float* __restrict__ r,
                                              const float* __restrict__ g,
                                              const float* __restrict__ be,
                                              float* __restrict__ outf) {
  long row = blockIdx.x;
  int tid = threadIdx.x;
  uint2 av = ((const uint2*)(a + row * 1024))[tid];
  float4 rv = ((const float4*)(r + row * 1024))[tid];
  float y[4];
  y[0] = bf2f((u16)(av.x & 0xffff)) + rv.x;
  y[1] = bf2f((u16)(av.x >> 16)) + rv.y;
  y[2] = bf2f((u16)(av.y & 0xffff)) + rv.z;
  y[3] = bf2f((u16)(av.y >> 16)) + rv.w;
  float s = y[0] + y[1] + y[2] + y[3];
  float q = y[0] * y[0] + y[1] * y[1] + y[2] * y[2] + y[3] * y[3];
#pragma unroll
  for (int o = 32; o > 0; o >>= 1) {
    s += __shfl_down(s, o);
    q += __shfl_down(q, o);
  }
  __shared__ float s1[4], s2[4];
  int wid = tid >> 6, lane = tid & 63;
  if (lane == 0) { s1[wid] = s; s2[wid] = q; }
  __syncthreads();
  s = s1[0] + s1[1] + s1[2] + s1[3];
  q = s2[0] + s2[1] + s2[2] + s2[3];
  float mu = s * (1.f / 1024.f);
  float var = q * (1.f / 1024.f) - mu * mu;
  float inv = rsqrtf(fmaxf(var, 0.f) + 1e-6f);
  float4 gv = ((const float4*)g)[tid], bv = ((const float4*)be)[tid];
  float o0 = gv.x * (y[0] - mu) * inv + bv.x;
  float o1 = gv.y * (y[1] - mu) * inv + bv.y;
  float o2 = gv.z * (y[2] - mu) * inv + bv.z;
  float o3 = gv.w * (y[3] - mu) * inv + bv.w;
  ((float4*)(outf + row * 1024))[tid] = make_float4(o0, o1, o2, o3);
}

extern "C" void kernel_launch(void* const* d_in, const int* in_sizes, int n_in,
                              void* d_out, int out_size, void* d_ws,
                              size_t ws_size, hipStream_t stream) {
  const float* x   = (const float*)d_in[0];
  const float* enc = (const float*)d_in[1];
  const float* wq1 = (const float*)d_in[2];  const float* bq1 = (const float*)d_in[3];
  const float* wk1 = (const float*)d_in[4];  const float* bk1 = (const float*)d_in[5];
  const float* wv1 = (const float*)d_in[6];  const float* bv1 = (const float*)d_in[7];
  const float* wo1 = (const float*)d_in[8];  const float* bo1 = (const float*)d_in[9];
  const float* wq2 = (const float*)d_in[10]; const float* bq2 = (const float*)d_in[11];
  const float* wk2 = (const float*)d_in[12]; const float* bk2 = (const float*)d_in[13];
  const float* wv2 = (const float*)d_in[14]; const float* bv2 = (const float*)d_in[15];
  const float* wo2 = (const float*)d_in[16]; const float* bo2 = (const float*)d_in[17];
  const float* wf1 = (const float*)d_in[18]; const float* bf1 = (const float*)d_in[19];
  const float* wf2 = (const float*)d_in[20]; const float* bf2 = (const float*)d_in[21];
  const float* g1 = (const float*)d_in[22];  const float* be1 = (const float*)d_in[23];
  const float* g2 = (const float*)d_in[24];  const float* be2 = (const float*)d_in[25];
  const float* g3 = (const float*)d_in[26];  const float* be3 = (const float*)d_in[27];
  (void)in_sizes; (void)n_in; (void)out_size; (void)ws_size;

  const size_t S = (size_t)16384 * 1024;  // tokens * d_model
  float* O0 = (float*)d_out;              // out3 (f32)

  char* base = (char*)d_ws;
  size_t off = 0;
  auto alloc = [&](size_t bytes) -> void* {
    void* p = base + off;
    off += (bytes + 255) & ~(size_t)255;
    return p;
  };
  u16* WT1    = (u16*)alloc((size_t)4096 * 1024 * 2);  // wf1^T bf16
  u16* WT2    = (u16*)alloc((size_t)4096 * 1024 * 2);  // wf2^T bf16
  float* qb   = (float*)alloc((size_t)16384 * 16 * 4);
  float* kb   = (float*)alloc((size_t)16384 * 16 * 4);
  float* ypart= (float*)alloc((size_t)4 * 32 * 16 * 1024 * 4);  // 8MB
  float* spart= (float*)alloc((size_t)4 * 8 * 16 * 4);
  float* kvb  = (float*)alloc((size_t)4 * 16 * 64 * 4);
  float* zb   = (float*)alloc((size_t)4 * 16 * 1024 * 4);       // 256KB
  u16* FA     = (u16*)alloc(S * 2);                    // bf16: ffn_out
  u16* FM     = (u16*)alloc((size_t)16384 * 4096 * 2); // bf16: ffn mid
  u16* O2b    = (u16*)alloc(S * 2);                    // bf16 out2
  float* O1f  = (float*)alloc(S * 4);                  // f32 out1
  float* O2f  = (float*)alloc(S * 4);                  // f32 out2

  const int T = 16384;
  dim3 blk(256), gblk(512);

  // ---- MHA1 (q=k=v from x, single x read) ----
  proj_mfma<1, 0><<<256, blk, 0, stream>>>(x, nullptr, wq1, bq1, wk1, bk1,
                                           qb, kb);
  ksum<<<dim3(8, 8, 4), blk, 0, stream>>>(kb, x, ypart, spart);
  kv_small<<<64, blk, 0, stream>>>(ypart, spart, wv1, bv1, kvb);
  zker<<<64, blk, 0, stream>>>(kvb, wo1, zb);
  ln_attn<1><<<1024, blk, 0, stream>>>(qb, zb, bo1, x, g1, be1, O1f, nullptr);

  // ---- MHA2 (q from out1 f32, k/v from enc f32) ----
  proj_mfma<0, 0><<<256, blk, 0, stream>>>(O1f, enc, wq2, bq2, wk2, bk2,
                                           qb, kb);
  ksum<<<dim3(8, 8, 4), blk, 0, stream>>>(kb, enc, ypart, spart);
  kv_small<<<64, blk, 0, stream>>>(ypart, spart, wv2, bv2, kvb);
  zker<<<64, blk, 0, stream>>>(kvb, wo2, zb);
  ln_attn<2><<<1024, blk, 0, stream>>>(qb, zb, bo2, O1f, g2, be2, O2f, O2b);

  // ---- FFN ----
  transpose_cvt<<<dim3(128, 32), blk, 0, stream>>>(wf1, WT1, 1024, 4096);
  transpose_cvt<<<dim3(32, 128), blk, 0, stream>>>(wf2, WT2, 4096, 1024);
  gemm256<1><<<dim3(32, 64), gblk, 0, stream>>>(O2b, WT1, bf1, FM, T, 4096, 1024);
  gemm256<0><<<dim3(8, 64), gblk, 0, stream>>>(FM, WT2, bf2, FA, T, 1024, 4096);
  ln_res<<<16384, blk, 0, stream>>>(FA, O2f, g3, be3, O0);  // out3

  // outputs 1 and 2 must be zeros
  hipMemsetAsync((float*)d_out + S, 0, 2 * S * 4, stream);
}

// Round 17
// 579.945 us; speedup vs baseline: 1.0582x; 1.0582x over previous
//
#include <hip/hip_runtime.h>
#include <cstdint>

typedef unsigned short u16;
typedef __bf16 bf16x8 __attribute__((ext_vector_type(8)));
typedef float f32x4 __attribute__((ext_vector_type(4)));

__device__ __forceinline__ float bf2f(u16 h) {
  union { uint32_t u; float f; } v; v.u = (uint32_t)h << 16; return v.f;
}
__device__ __forceinline__ u16 f2bf(float f) {
  union { float f; uint32_t u; } v; v.f = f;
  uint32_t r = v.u + 0x7fffu + ((v.u >> 16) & 1u);
  return (u16)(r >> 16);
}
__device__ __forceinline__ float sigmoidf_(float x) {
  return 1.0f / (1.0f + __expf(-x));
}
__device__ __forceinline__ void load_lds16(const void* g, void* l) {
  __builtin_amdgcn_global_load_lds(
      (const __attribute__((address_space(1))) void*)g,
      (__attribute__((address_space(3))) void*)l, 16, 0, 0);
}
__device__ __forceinline__ bf16x8 cvt8(const float* p) {
  float4 a = *(const float4*)p, b = *(const float4*)(p + 4);
  union { u16 u[8]; bf16x8 v; } r;
  r.u[0] = f2bf(a.x); r.u[1] = f2bf(a.y); r.u[2] = f2bf(a.z); r.u[3] = f2bf(a.w);
  r.u[4] = f2bf(b.x); r.u[5] = f2bf(b.y); r.u[6] = f2bf(b.z); r.u[7] = f2bf(b.w);
  return r.v;
}
#define BAR() __builtin_amdgcn_s_barrier()

// ------------- transpose+convert: in f32 [K][N] -> out bf16 [N][K] -------
__global__ __launch_bounds__(256) void transpose_cvt(
    const float* __restrict__ in, u16* __restrict__ out, int K, int N) {
  __shared__ float t[32][33];
  int n0 = blockIdx.x * 32, k0 = blockIdx.y * 32;
  int tx = threadIdx.x & 31, ty = threadIdx.x >> 5;
#pragma unroll
  for (int i = 0; i < 32; i += 8)
    t[ty + i][tx] = in[(long)(k0 + ty + i) * N + n0 + tx];
  __syncthreads();
#pragma unroll
  for (int i = 0; i < 32; i += 8)
    out[(long)(n0 + ty + i) * K + k0 + tx] = f2bf(t[tx][ty + i]);
}

// ===== MFMA projection: q = xq@wq+bq, k = xk@wk+bk ; [T,1024]->[T,16]x2 ===
template <int SAME, int QBF>
__global__ __launch_bounds__(256) void proj_mfma(
    const void* __restrict__ xq_, const float* __restrict__ xk,
    const float* __restrict__ wq, const float* __restrict__ bq,
    const float* __restrict__ wk, const float* __restrict__ bk,
    float* __restrict__ qout, float* __restrict__ kout) {
  __shared__ __attribute__((aligned(16))) u16 wt[2][16384];  // 64KB
  const int tid = threadIdx.x;
  for (int kq = 0; kq < 4; kq++) {
    int k = kq * 256 + tid;
    const float4* q4 = (const float4*)(wq + (long)k * 16);
    const float4* k4 = (const float4*)(wk + (long)k * 16);
#pragma unroll
    for (int p = 0; p < 4; p++) {
      float4 qv = q4[p], kv = k4[p];
      float qf[4] = {qv.x, qv.y, qv.z, qv.w};
      float kf[4] = {kv.x, kv.y, kv.z, kv.w};
#pragma unroll
      for (int j = 0; j < 4; j++) {
        int c = p * 4 + j;
        int off = (c * 2048 + k * 2) ^ ((c & 7) << 4);
        *(u16*)((char*)wt[0] + off) = f2bf(qf[j]);
        *(u16*)((char*)wt[1] + off) = f2bf(kf[j]);
      }
    }
  }
  __syncthreads();
  const int wv = tid >> 6, lane = tid & 63;
  const int lrow = lane & 15, g = lane >> 4;
  const long tok0 = (long)blockIdx.x * 64 + wv * 16;
  const int swz = (lrow & 7) << 4;
  const long arow = (tok0 + lrow) * 1024 + g * 8;
  f32x4 accq = {}, acck = {};
#pragma unroll 8
  for (int ks = 0; ks < 32; ks++) {
    bf16x8 aq_;
    if (QBF)
      aq_ = *(const bf16x8*)((const u16*)xq_ + arow + ks * 32);
    else
      aq_ = cvt8((const float*)xq_ + arow + ks * 32);
    bf16x8 ak_;
    if (SAME)
      ak_ = aq_;
    else
      ak_ = cvt8(xk + arow + ks * 32);
    int off = (lrow * 2048 + ks * 64 + g * 16) ^ swz;
    bf16x8 bq_ = *(const bf16x8*)((const char*)wt[0] + off);
    bf16x8 bk_ = *(const bf16x8*)((const char*)wt[1] + off);
    accq = __builtin_amdgcn_mfma_f32_16x16x32_bf16(aq_, bq_, accq, 0, 0, 0);
    acck = __builtin_amdgcn_mfma_f32_16x16x32_bf16(ak_, bk_, acck, 0, 0, 0);
  }
  const int col = lrow, r0 = g * 4;
  float bqv = bq[col], bkv = bk[col];
#pragma unroll
  for (int i = 0; i < 4; i++) {
    qout[(tok0 + r0 + i) * 16 + col] = accq[i] + bqv;
    kout[(tok0 + r0 + i) * 16 + col] = acck[i] + bkv;
  }
}

// ===== ksum: y_part[b][p][h][c] = Σ_{s in chunk} σ(k[b,s,h])·x[b,s,c] ====
__global__ __launch_bounds__(256) void ksum(const float* __restrict__ kp,
                                            const float* __restrict__ x,
                                            float* __restrict__ ypart,
                                            float* __restrict__ spart) {
  __shared__ __attribute__((aligned(16))) float sk[256][20];
  __shared__ float ssl[16][17];
  const int tid = threadIdx.x;
  const int cc = blockIdx.x, sc = blockIdx.y, b = blockIdx.z;
  const int cl = tid & 63, sg = tid >> 6;
  const int col0 = cc * 128 + cl;
  float acc0[16], acc1[16];
#pragma unroll
  for (int h = 0; h < 16; h++) { acc0[h] = 0.f; acc1[h] = 0.f; }
  float ss = 0.f;
  for (int tile = 0; tile < 2; tile++) {
    const int s0 = sc * 512 + tile * 256;
    const float* kr = kp + ((long)b * 4096 + s0 + tid) * 16;
#pragma unroll
    for (int p = 0; p < 4; p++) {
      float4 k4 = *(const float4*)(kr + p * 4);
      *(float4*)&sk[tid][p * 4] = make_float4(
          sigmoidf_(k4.x), sigmoidf_(k4.y), sigmoidf_(k4.z), sigmoidf_(k4.w));
    }
    __syncthreads();
    {
      int g2 = tid >> 4, h2 = tid & 15;
      float s_ = 0.f;
#pragma unroll
      for (int i = 0; i < 16; i++) s_ += sk[g2 * 16 + i][h2];
      ssl[g2][h2] = s_;
    }
    __syncthreads();
    if (tid < 16) {
      float s_ = 0.f;
#pragma unroll
      for (int gg = 0; gg < 16; gg++) s_ += ssl[gg][tid];
      ss += s_;
    }
    const float* xr = x + ((long)b * 4096 + s0 + sg * 64) * 1024 + col0;
    for (int j = 0; j < 64; j++) {
      float xv0 = xr[(long)j * 1024];
      float xv1 = xr[(long)j * 1024 + 64];
      const float4* skr = (const float4*)sk[sg * 64 + j];
#pragma unroll
      for (int p = 0; p < 4; p++) {
        float4 s4 = skr[p];
        acc0[p * 4 + 0] += s4.x * xv0; acc1[p * 4 + 0] += s4.x * xv1;
        acc0[p * 4 + 1] += s4.y * xv0; acc1[p * 4 + 1] += s4.y * xv1;
        acc0[p * 4 + 2] += s4.z * xv0; acc1[p * 4 + 2] += s4.z * xv1;
        acc0[p * 4 + 3] += s4.w * xv0; acc1[p * 4 + 3] += s4.w * xv1;
      }
    }
    __syncthreads();
  }
  long pbase = (long)(b * 32 + sc * 4 + sg) * 16384 + col0;
#pragma unroll
  for (int h = 0; h < 16; h++) {
    ypart[pbase + h * 1024] = acc0[h];
    ypart[pbase + h * 1024 + 64] = acc1[h];
  }
  if (tid < 16) spart[(b * 8 + sc) * 16 + tid] = ss;
}

// ===== kv[b,h,d] = (Σ_p y_part)·wv[:,h*64+d] + (Σσ)·bv[h*64+d] ===========
__global__ __launch_bounds__(256) void kv_small(
    const float* __restrict__ ypart, const float* __restrict__ spart,
    const float* __restrict__ wvw, const float* __restrict__ bv,
    float* __restrict__ kv) {
  __shared__ float yl[1024];
  __shared__ float red[4][64];
  const int tid = threadIdx.x;
  const int b = blockIdx.x >> 4, h = blockIdx.x & 15;
  for (int c = tid; c < 1024; c += 256) {
    float s_ = 0.f;
    const float* yp = ypart + (long)(b * 32) * 16384 + h * 1024 + c;
#pragma unroll
    for (int p = 0; p < 32; p++) s_ += yp[(long)p * 16384];
    yl[c] = s_;
  }
  __syncthreads();
  const int wv_ = tid >> 6, d = tid & 63;
  float acc = 0.f;
  const float* wcol = wvw + h * 64 + d;
  for (int c = wv_ * 256; c < wv_ * 256 + 256; c++)
    acc += yl[c] * wcol[(long)c * 1024];
  red[wv_][d] = acc;
  __syncthreads();
  if (tid < 64) {
    float ss = 0.f;
#pragma unroll
    for (int s_ = 0; s_ < 8; s_++) ss += spart[(b * 8 + s_) * 16 + h];
    kv[(b * 16 + h) * 64 + tid] = red[0][tid] + red[1][tid] + red[2][tid] +
                                  red[3][tid] + ss * bv[h * 64 + tid];
  }
}

// ===== z[b,h,n] = Σ_d cumsum_h(kv)[b,h,d]·wo[h*64+d, n]  (cumsum fused) ===
__global__ __launch_bounds__(256) void zker(const float* __restrict__ kvb,
                                            const float* __restrict__ wo,
                                            float* __restrict__ z) {
  __shared__ float sc_[64];
  const int tid = threadIdx.x;
  const int b = blockIdx.x >> 4, h = blockIdx.x & 15;
  if (tid < 64) {
    float run = 0.f;
    for (int hh = 0; hh <= h; hh++) run += kvb[(b * 16 + hh) * 64 + tid];
    sc_[tid] = run;
  }
  __syncthreads();
  float4 acc = make_float4(0.f, 0.f, 0.f, 0.f);
  for (int d = 0; d < 64; d++) {
    float s_ = sc_[d];
    float4 w = ((const float4*)(wo + (long)(h * 64 + d) * 1024))[tid];
    acc.x += s_ * w.x; acc.y += s_ * w.y;
    acc.z += s_ * w.z; acc.w += s_ * w.w;
  }
  ((float4*)(z + (long)(b * 16 + h) * 1024))[tid] = acc;
}

// ===== fused attn-broadcast + residual + LayerNorm ========================
// OMODE 1: f32 out only; 2: f32 + bf16; 3: bf16 only
template <int OMODE>
__global__ __launch_bounds__(256) void ln_attn(
    const float* __restrict__ qp, const float* __restrict__ z,
    const float* __restrict__ bo, const float* __restrict__ r,
    const float* __restrict__ g, const float* __restrict__ be,
    float* __restrict__ outf, u16* __restrict__ outb) {
  __shared__ float zs[16][1024];
  __shared__ float sq16[16];
  __shared__ float s1[4], s2[4];
  const int tid = threadIdx.x;
  const int b = blockIdx.x >> 8;
  const float4* zg = (const float4*)(z + (long)b * 16384);
  float4* zl = (float4*)zs;
#pragma unroll
  for (int i = 0; i < 16; i++) zl[i * 256 + tid] = zg[i * 256 + tid];
  float4 gv = ((const float4*)g)[tid];
  float4 bev = ((const float4*)be)[tid];
  float4 bov = ((const float4*)bo)[tid];
  const int wid = tid >> 6, lane = tid & 63;
  for (int rr_ = 0; rr_ < 16; rr_++) {
    long row = (long)blockIdx.x * 16 + rr_;
    if (tid < 16) sq16[tid] = sigmoidf_(qp[row * 16 + tid]);
    __syncthreads();
    float4 rv = ((const float4*)(r + row * 1024))[tid];
    float y0 = bov.x + rv.x, y1 = bov.y + rv.y;
    float y2 = bov.z + rv.z, y3 = bov.w + rv.w;
#pragma unroll
    for (int h = 0; h < 16; h++) {
      float s_ = sq16[h];
      float4 zv = *(const float4*)&zs[h][tid * 4];
      y0 += s_ * zv.x; y1 += s_ * zv.y; y2 += s_ * zv.z; y3 += s_ * zv.w;
    }
    float s = y0 + y1 + y2 + y3;
    float q = y0 * y0 + y1 * y1 + y2 * y2 + y3 * y3;
#pragma unroll
    for (int o = 32; o > 0; o >>= 1) {
      s += __shfl_down(s, o);
      q += __shfl_down(q, o);
    }
    if (lane == 0) { s1[wid] = s; s2[wid] = q; }
    __syncthreads();
    s = s1[0] + s1[1] + s1[2] + s1[3];
    q = s2[0] + s2[1] + s2[2] + s2[3];
    float mu = s * (1.f / 1024.f);
    float var = q * (1.f / 1024.f) - mu * mu;
    float inv = rsqrtf(fmaxf(var, 0.f) + 1e-6f);
    float o0 = gv.x * (y0 - mu) * inv + bev.x;
    float o1 = gv.y * (y1 - mu) * inv + bev.y;
    float o2 = gv.z * (y2 - mu) * inv + bev.z;
    float o3 = gv.w * (y3 - mu) * inv + bev.w;
    if (OMODE != 3)
      ((float4*)(outf + row * 1024))[tid] = make_float4(o0, o1, o2, o3);
    if (OMODE >= 2) {
      uint2 ob;
      ob.x = (uint32_t)f2bf(o0) | ((uint32_t)f2bf(o1) << 16);
      ob.y = (uint32_t)f2bf(o2) | ((uint32_t)f2bf(o3) << 16);
      ((uint2*)(outb + row * 1024))[tid] = ob;
    }
    __syncthreads();
  }
}

// ===== 256x256 MFMA GEMM — r15 (best: 4-phase/ktile, 2-bit XOR swizzle) ===
template <int ACT>
__global__ __launch_bounds__(512) void gemm256(
    const u16* __restrict__ A, const u16* __restrict__ BT,
    const float* __restrict__ bias, u16* __restrict__ C, int M, int N,
    int K) {
  __shared__ __attribute__((aligned(16))) u16 lds[65536];  // 128 KB
  const int tid = threadIdx.x;
  const int wid = tid >> 6, lane = tid & 63;
  const int wm = wid >> 2, wn = wid & 3;
  const int lrow = lane & 15, g = lane >> 4;

  int nwg = gridDim.x * gridDim.y;
  int orig = blockIdx.y * gridDim.x + blockIdx.x;
  int wg = (nwg & 7) ? orig : ((orig & 7) * (nwg >> 3) + (orig >> 3));
  const long bn = (long)(wg % gridDim.x) * 256;
  const long bm = (long)(wg / gridDim.x) * 256;

  const int rr = wid * 16 + (lane >> 2);
  const int esrc = (((lane & 3) ^ ((lane >> 3) & 3)) * 8);
  const u16* Abase = A + (bm + rr) * (long)K + esrc;
  const u16* Bbase = BT + (bn + rr) * (long)K + esrc;
  const long jstep = (long)128 * K;
  char* ldsc = (char*)lds;
  const int ldsw = wid * 1024;

  const int slotr = (g ^ ((lrow >> 1) & 3)) * 16;
  const int aoff = (wm * 128 + lrow) * 64 + slotr;
  const int boff = 32768 + (wn * 64 + lrow) * 64 + slotr;

  f32x4 acc[8][4] = {};
  const int KT = K >> 6;

  auto stage2 = [&](int buf, int kk, int kt, int half) {
    int dA = buf * 65536 + kk * 16384 + ldsw;
    if (half == 0) {
      const u16* sA = Abase + (long)kt * 64 + kk * 32;
      load_lds16(sA, ldsc + dA);
      load_lds16(sA + jstep, ldsc + dA + 8192);
    } else {
      const u16* sB = Bbase + (long)kt * 64 + kk * 32;
      load_lds16(sB, ldsc + dA + 32768);
      load_lds16(sB + jstep, ldsc + dA + 40960);
    }
  };

#define LDAB8(BUF, KK)                                                      \
  {                                                                         \
    const char* _b = ldsc + (BUF) * 65536 + (KK) * 16384;                   \
    _Pragma("unroll") for (int m = 0; m < 4; m++)                           \
        af[m] = *(const bf16x8*)(_b + aoff + m * 1024);                     \
    _Pragma("unroll") for (int n = 0; n < 4; n++)                           \
        bq[n] = *(const bf16x8*)(_b + boff + n * 1024);                     \
  }
#define LDA4(BUF, KK)                                                       \
  {                                                                         \
    const char* _b = ldsc + (BUF) * 65536 + (KK) * 16384;                   \
    _Pragma("unroll") for (int m = 4; m < 8; m++)                           \
        af[m] = *(const bf16x8*)(_b + aoff + m * 1024);                     \
  }
#define MMA16(M0)                                                           \
  __builtin_amdgcn_s_setprio(1);                                            \
  _Pragma("unroll") for (int m = M0; m < M0 + 4; m++)                       \
  _Pragma("unroll") for (int n = 0; n < 4; n++)                             \
      acc[m][n] = __builtin_amdgcn_mfma_f32_16x16x32_bf16(af[m], bq[n],     \
                                                          acc[m][n], 0, 0,  \
                                                          0);               \
  __builtin_amdgcn_s_setprio(0);
#define WLG0() asm volatile("s_waitcnt lgkmcnt(0)" ::: "memory")
#define WVM4() asm volatile("s_waitcnt vmcnt(4)" ::: "memory")
#define WVM0() asm volatile("s_waitcnt vmcnt(0)" ::: "memory")

  bf16x8 af[8], bq[4];

  stage2(0, 0, 0, 0);
  stage2(0, 0, 0, 1);
  stage2(0, 1, 0, 0);
  stage2(0, 1, 0, 1);
  WVM4();
  BAR();

  for (int kt = 0; kt + 1 < KT; ++kt) {
    const int b0 = kt & 1, b1 = b0 ^ 1;
    LDAB8(b0, 0);
    stage2(b1, 0, kt + 1, 0);
    BAR(); WLG0();
    MMA16(0);
    BAR();
    LDA4(b0, 0);
    stage2(b1, 0, kt + 1, 1);
    WVM4();
    BAR(); WLG0();
    MMA16(4);
    BAR();
    LDAB8(b0, 1);
    stage2(b1, 1, kt + 1, 0);
    BAR(); WLG0();
    MMA16(0);
    BAR();
    LDA4(b0, 1);
    stage2(b1, 1, kt + 1, 1);
    WVM4();
    BAR(); WLG0();
    MMA16(4);
    BAR();
  }
  {
    const int b0 = (KT - 1) & 1;
    LDAB8(b0, 0);
    BAR(); WLG0();
    MMA16(0);
    BAR();
    LDA4(b0, 0);
    WVM0();
    BAR(); WLG0();
    MMA16(4);
    BAR();
    LDAB8(b0, 1);
    BAR(); WLG0();
    MMA16(0);
    BAR();
    LDA4(b0, 1);
    BAR(); WLG0();
    MMA16(4);
    BAR();
  }

#pragma unroll
  for (int n = 0; n < 4; n++) {
    int cl = wn * 64 + n * 16 + lrow;
    float bb = bias[bn + cl];
#pragma unroll
    for (int m = 0; m < 8; m++) {
      int rl = wm * 128 + m * 16 + g * 4;
#pragma unroll
      for (int i = 0; i < 4; i++) {
        float v = acc[m][n][i] + bb;
        if (ACT == 1) v = fmaxf(v, 0.f);
        lds[(rl + i) * 256 + cl] = f2bf(v);
      }
    }
  }
  BAR();
  const uint4* lv = (const uint4*)lds;
#pragma unroll
  for (int it = 0; it < 16; it++) {
    int idx = it * 512 + tid;
    int row = idx >> 5;
    int cu = (idx & 31) * 8;
    *(uint4*)&C[(bm + row) * (long)N + bn + cu] = lv[idx];
  }
#undef LDAB8
#undef LDA4
#undef MMA16
#undef WLG0
#undef WVM4
#undef WVM0
}

// --- LayerNorm(a_bf16 + r_bf16)*g + be -> f32 -----------------------------
__global__ __launch_bounds__(256) void ln_res(const u16* __restrict__ a,
                                              const u16* __restrict__ r,
                                              const float* __restrict__ g,
                                              const float* __restrict__ be,
                                              float* __restrict__ outf) {
  long row = blockIdx.x;
  int tid = threadIdx.x;
  uint2 av = ((const uint2*)(a + row * 1024))[tid];
  uint2 rv = ((const uint2*)(r + row * 1024))[tid];
  float y[4];
  y[0] = bf2f((u16)(av.x & 0xffff)) + bf2f((u16)(rv.x & 0xffff));
  y[1] = bf2f((u16)(av.x >> 16)) + bf2f((u16)(rv.x >> 16));
  y[2] = bf2f((u16)(av.y & 0xffff)) + bf2f((u16)(rv.y & 0xffff));
  y[3] = bf2f((u16)(av.y >> 16)) + bf2f((u16)(rv.y >> 16));
  float s = y[0] + y[1] + y[2] + y[3];
  float q = y[0] * y[0] + y[1] * y[1] + y[2] * y[2] + y[3] * y[3];
#pragma unroll
  for (int o = 32; o > 0; o >>= 1) {
    s += __shfl_down(s, o);
    q += __shfl_down(q, o);
  }
  __shared__ float s1[4], s2[4];
  int wid = tid >> 6, lane = tid & 63;
  if (lane == 0) { s1[wid] = s; s2[wid] = q; }
  __syncthreads();
  s = s1[0] + s1[1] + s1[2] + s1[3];
  q = s2[0] + s2[1] + s2[2] + s2[3];
  float mu = s * (1.f / 1024.f);
  float var = q * (1.f / 1024.f) - mu * mu;
  float inv = rsqrtf(fmaxf(var, 0.f) + 1e-6f);
  float4 gv = ((const float4*)g)[tid], bv = ((const float4*)be)[tid];
  float o0 = gv.x * (y[0] - mu) * inv + bv.x;
  float o1 = gv.y * (y[1] - mu) * inv + bv.y;
  float o2 = gv.z * (y[2] - mu) * inv + bv.z;
  float o3 = gv.w * (y[3] - mu) * inv + bv.w;
  ((float4*)(outf + row * 1024))[tid] = make_float4(o0, o1, o2, o3);
}

extern "C" void kernel_launch(void* const* d_in, const int* in_sizes, int n_in,
                              void* d_out, int out_size, void* d_ws,
                              size_t ws_size, hipStream_t stream) {
  const float* x   = (const float*)d_in[0];
  const float* enc = (const float*)d_in[1];
  const float* wq1 = (const float*)d_in[2];  const float* bq1 = (const float*)d_in[3];
  const float* wk1 = (const float*)d_in[4];  const float* bk1 = (const float*)d_in[5];
  const float* wv1 = (const float*)d_in[6];  const float* bv1 = (const float*)d_in[7];
  const float* wo1 = (const float*)d_in[8];  const float* bo1 = (const float*)d_in[9];
  const float* wq2 = (const float*)d_in[10]; const float* bq2 = (const float*)d_in[11];
  const float* wk2 = (const float*)d_in[12]; const float* bk2 = (const float*)d_in[13];
  const float* wv2 = (const float*)d_in[14]; const float* bv2 = (const float*)d_in[15];
  const float* wo2 = (const float*)d_in[16]; const float* bo2 = (const float*)d_in[17];
  const float* wf1 = (const float*)d_in[18]; const float* bf1 = (const float*)d_in[19];
  const float* wf2 = (const float*)d_in[20]; const float* bf2 = (const float*)d_in[21];
  const float* g1 = (const float*)d_in[22];  const float* be1 = (const float*)d_in[23];
  const float* g2 = (const float*)d_in[24];  const float* be2 = (const float*)d_in[25];
  const float* g3 = (const float*)d_in[26];  const float* be3 = (const float*)d_in[27];
  (void)in_sizes; (void)n_in; (void)out_size; (void)ws_size;

  const size_t S = (size_t)16384 * 1024;  // tokens * d_model
  float* O0 = (float*)d_out;              // out3 (f32)

  char* base = (char*)d_ws;
  size_t off = 0;
  auto alloc = [&](size_t bytes) -> void* {
    void* p = base + off;
    off += (bytes + 255) & ~(size_t)255;
    return p;
  };
  u16* WT1    = (u16*)alloc((size_t)4096 * 1024 * 2);  // wf1^T bf16
  u16* WT2    = (u16*)alloc((size_t)4096 * 1024 * 2);  // wf2^T bf16
  float* qb   = (float*)alloc((size_t)16384 * 16 * 4);
  float* kb   = (float*)alloc((size_t)16384 * 16 * 4);
  float* ypart= (float*)alloc((size_t)4 * 32 * 16 * 1024 * 4);  // 8MB
  float* spart= (float*)alloc((size_t)4 * 8 * 16 * 4);
  float* kvb  = (float*)alloc((size_t)4 * 16 * 64 * 4);
  float* zb   = (float*)alloc((size_t)4 * 16 * 1024 * 4);       // 256KB
  u16* FA     = (u16*)alloc(S * 2);                    // bf16: ffn_out
  u16* FM     = (u16*)alloc((size_t)16384 * 4096 * 2); // bf16: ffn mid
  u16* O2b    = (u16*)alloc(S * 2);                    // bf16 out2
  float* O1f  = (float*)alloc(S * 4);                  // f32 out1

  const int T = 16384;
  dim3 blk(256), gblk(512);

  // ---- MHA1 (q=k=v from x, single x read) ----
  proj_mfma<1, 0><<<256, blk, 0, stream>>>(x, nullptr, wq1, bq1, wk1, bk1,
                                           qb, kb);
  ksum<<<dim3(8, 8, 4), blk, 0, stream>>>(kb, x, ypart, spart);
  kv_small<<<64, blk, 0, stream>>>(ypart, spart, wv1, bv1, kvb);
  zker<<<64, blk, 0, stream>>>(kvb, wo1, zb);
  ln_attn<1><<<1024, blk, 0, stream>>>(qb, zb, bo1, x, g1, be1, O1f, nullptr);

  // ---- MHA2 (q from out1 f32, k/v from enc f32) ----
  proj_mfma<0, 0><<<256, blk, 0, stream>>>(O1f, enc, wq2, bq2, wk2, bk2,
                                           qb, kb);
  ksum<<<dim3(8, 8, 4), blk, 0, stream>>>(kb, enc, ypart, spart);
  kv_small<<<64, blk, 0, stream>>>(ypart, spart, wv2, bv2, kvb);
  zker<<<64, blk, 0, stream>>>(kvb, wo2, zb);
  ln_attn<3><<<1024, blk, 0, stream>>>(qb, zb, bo2, O1f, g2, be2, nullptr,
                                       O2b);  // out2 bf16 only

  // ---- FFN ----
  transpose_cvt<<<dim3(128, 32), blk, 0, stream>>>(wf1, WT1, 1024, 4096);
  transpose_cvt<<<dim3(32, 128), blk, 0, stream>>>(wf2, WT2, 4096, 1024);
  gemm256<1><<<dim3(16, 64), gblk, 0, stream>>>(O2b, WT1, bf1, FM, T, 4096, 1024);
  gemm256<0><<<dim3(4, 64), gblk, 0, stream>>>(FM, WT2, bf2, FA, T, 1024, 4096);
  ln_res<<<16384, blk, 0, stream>>>(FA, O2b, g3, be3, O0);  // out3

  // outputs 1 and 2 must be zeros
  hipMemsetAsync((float*)d_out + S, 0, 2 * S * 4, stream);
}